// Round 10
// baseline (615.343 us; speedup 1.0000x reference)
//
#include <hip/hip_runtime.h>
#include <hip/hip_bf16.h>
#include <math.h>

// Layer_67637144978060 — chunked linear-RNN, bf16 MFMA GEMMs, parallel scan,
// 2-phase double-buffered K-loop (BK=32, stage-next-before-compute, T3 minimum).
// S_0 = W;  reads_t = S_t @ out_t;  S_{t+1} = e^lg S_t + v_t (x) wk_t;  W_new = S_T.
// CH=1024 (NC=4): rmsnorm, v-proj, transposes, P_ch GEMM, scores (tri blocks),
// Horner comb (Sch over dead wkTw), FUSED reads = e^{lg tc}*(out@Sch^T) + scores@v
// (single acc: S-part first, in-register row scale, then tri-truncated intra part),
// final projection. Workspace 196.1 MB. LDS 32 KB/block (2x 8KB dbuf x A,B).

typedef __hip_bfloat16 bf16;
typedef short bf16x8 __attribute__((ext_vector_type(8)));
typedef float f32x4 __attribute__((ext_vector_type(4)));

#define TPB 256
#define LC 10
#define CH (1 << LC)   // chunk length 1024

__device__ __forceinline__ void gload_lds16(const void* g, void* l) {
  __builtin_amdgcn_global_load_lds(
      (const __attribute__((address_space(1))) unsigned int*)g,
      (__attribute__((address_space(3))) unsigned int*)l, 16, 0, 0);
}

enum { E_BF = 0, E_SCORES, E_P, E_RDF, E_FINAL };

struct MGP {
  const bf16 *A, *B;    // primary GEMM operands (E_RDF: scores / vT, phase 2)
  const bf16 *A2, *B2;  // E_RDF phase-1 operands (out_pad / Sch)
  float *Cf; bf16 *Cb;
  const float *X; const bf16 *O;
  const float *dec;
  int K, K2;
  int lda, ldb, lda2, ldb2, ldc;
  long sAb, sBb, sA2b, sB2b, sCfb, sCbb, sOb, sCkb;
  int NC, aOff0, aStep, bOff0, bStep, a2Off0, a2Step, b2Step;
};

// stage one 128x32 bf16 tile pair into (lA,lB) [8 KB each]; source pre-swizzled (#21)
__device__ __forceinline__ void stage32(const bf16* Ab, int lda, const bf16* Bb, int ldb,
                                        int k0, char* lA, char* lB, int w, int lane) {
#pragma unroll
  for (int c = 0; c < 2; c++) {
    const int o = c * 4096 + w * 1024 + lane * 16;          // linear LDS byte offset
    const int row = o >> 6;                                  // 64B rows (32 bf16)
    const int cols = ((o & 63) ^ (((row >> 1) & 3) << 4)) >> 1;  // swizzled col (elems)
    gload_lds16(Ab + (long)row * lda + k0 + cols, lA + c * 4096 + w * 1024);
    gload_lds16(Bb + (long)row * ldb + k0 + cols, lB + c * 4096 + w * 1024);
  }
}

// one BK=32 step: 4+4 swizzled ds_read_b128 + 16 MFMA
__device__ __forceinline__ void comp32(const char* lA, const char* lB,
                                       int wr, int wc, int lane, f32x4 (&acc)[4][4]) {
  bf16x8 af[4], bfr[4];
  const int j = lane >> 4;                                   // k-slot 0..3
#pragma unroll
  for (int f = 0; f < 4; f++) {
    const int rA = wr * 64 + f * 16 + (lane & 15);
    af[f] = *(const bf16x8*)(lA + rA * 64 + ((j ^ ((rA >> 1) & 3)) << 4));
    const int rB = wc * 64 + f * 16 + (lane & 15);
    bfr[f] = *(const bf16x8*)(lB + rB * 64 + ((j ^ ((rB >> 1) & 3)) << 4));
  }
#pragma unroll
  for (int fm = 0; fm < 4; fm++)
#pragma unroll
    for (int fn = 0; fn < 4; fn++)
      acc[fm][fn] = __builtin_amdgcn_mfma_f32_16x16x32_bf16(af[fm], bfr[fn], acc[fm][fn], 0, 0, 0);
}

// double-buffered pipelined K-loop; Kend multiple of 64 (NT even); ends with barrier
__device__ __forceinline__ void gemm_pipe(const bf16* Ab, int lda, const bf16* Bb, int ldb,
                                          int Kend, char* ldsA, char* ldsB,
                                          int w, int lane, int wr, int wc, f32x4 (&acc)[4][4]) {
  stage32(Ab, lda, Bb, ldb, 0, ldsA, ldsB, w, lane);
  __syncthreads();
  const int NT = Kend >> 5;
  for (int t = 0; t < NT; t += 2) {
    stage32(Ab, lda, Bb, ldb, (t + 1) * 32, ldsA + 8192, ldsB + 8192, w, lane);  // prefetch
    comp32(ldsA, ldsB, wr, wc, lane, acc);                                        // overlaps
    __syncthreads();
    if (t + 2 < NT) stage32(Ab, lda, Bb, ldb, (t + 2) * 32, ldsA, ldsB, w, lane);
    comp32(ldsA + 8192, ldsB + 8192, wr, wc, lane, acc);
    __syncthreads();
  }
}

template<int MODE>
__global__ __launch_bounds__(TPB) void mg_k(MGP p) {
  __shared__ __align__(16) char ldsA[2 * 8192];
  __shared__ __align__(16) char ldsB[2 * 8192];
  const int tid = threadIdx.x;
  const int lane = tid & 63;
  const int w = tid >> 6;
  const int wr = w >> 1, wc = w & 1;
  const int z = blockIdx.z;
  const int b = z / p.NC, ch = z - b * p.NC;
  const int m0 = blockIdx.x * 128, n0 = blockIdx.y * 128;
  if constexpr (MODE == E_SCORES) {
    if (n0 > m0) return;               // fully-masked block (n >= m ⇒ mask 0)
  }
  const float lg = -log1pf(expf(-p.dec[0]));   // log(sigmoid(decay))

  f32x4 acc[4][4];
#pragma unroll
  for (int i = 0; i < 4; i++)
#pragma unroll
    for (int j = 0; j < 4; j++) acc[i][j] = (f32x4){0.f, 0.f, 0.f, 0.f};

  if constexpr (MODE == E_RDF) {
    // phase 1: acc = out_ch @ Sch^T  (K = K2 = D)
    const bf16* A2 = p.A2 + b * p.sA2b + ((long)(p.a2Off0 + ch * p.a2Step) + m0) * p.lda2;
    const bf16* B2 = p.B2 + b * p.sB2b + ((long)(ch * p.b2Step) + n0) * p.ldb2;
    gemm_pipe(A2, p.lda2, B2, p.ldb2, p.K2, ldsA, ldsB, w, lane, wr, wc, acc);
    // in-register row scale: acc *= e^{lg * tc}   (tc = local chunk row)
#pragma unroll
    for (int fm = 0; fm < 4; fm++)
#pragma unroll
      for (int r = 0; r < 4; r++) {
        const int mrow = m0 + wr * 64 + fm * 16 + ((lane >> 4) << 2) + r;
        const float sc = __expf(lg * (float)mrow);
#pragma unroll
        for (int fn = 0; fn < 4; fn++) acc[fm][fn][r] *= sc;
      }
  }

  // main GEMM (E_RDF: phase 2, K truncated at diagonal)
  {
    const bf16* Ab = p.A + b * p.sAb + ((long)(p.aOff0 + ch * p.aStep) + m0) * p.lda;
    const bf16* Bb = p.B + b * p.sBb + ((long)(p.bOff0 + ch * p.bStep) + n0) * p.ldb;
    const int Kend = (MODE == E_RDF) ? (m0 + 128 < p.K ? m0 + 128 : p.K) : p.K;
    gemm_pipe(Ab, p.lda, Bb, p.ldb, Kend, ldsA, ldsB, w, lane, wr, wc, acc);
  }

  // ---- epilogue: C/D map col=lane&15, row=(lane>>4)*4+r [m89] ----
#pragma unroll
  for (int fm = 0; fm < 4; fm++) {
#pragma unroll
    for (int fn = 0; fn < 4; fn++) {
#pragma unroll
      for (int r = 0; r < 4; r++) {
        const int m = m0 + wr * 64 + fm * 16 + ((lane >> 4) << 2) + r;
        const int n = n0 + wc * 64 + fn * 16 + (lane & 15);
        const float vacc = acc[fm][fn][r];
        if constexpr (MODE == E_BF) {
          p.Cb[b * p.sCbb + (long)m * p.ldc + n] = __float2bfloat16(vacc);
        } else if constexpr (MODE == E_SCORES) {
          const float sv = (n < m) ? vacc * __expf(lg * (float)(m - 1 - n)) : 0.f;
          p.Cb[b * p.sCbb + ch * p.sCkb + (long)m * p.ldc + n] = __float2bfloat16(sv);
        } else if constexpr (MODE == E_P) {
          p.Cb[b * p.sCbb + ch * p.sCkb + (long)m * p.ldc + n] = __float2bfloat16(vacc);
        } else if constexpr (MODE == E_RDF) {
          p.Cb[b * p.sCbb + ch * p.sCkb + (long)m * p.ldc + n] = __float2bfloat16(vacc);
        } else {  // E_FINAL
          const long idx = b * p.sCfb + (long)m * p.ldc + n;
          const float ov = __bfloat162float(p.O[b * p.sOb + (long)(m + 1) * p.ldc + n]);
          p.Cf[idx] = p.X[idx] + ov + 0.03f * vacc;
        }
      }
    }
  }
}

// RMSNorm: one block per row, writes bf16 into padded layout row t+1
__global__ __launch_bounds__(256) void rmsnorm_k(const float* __restrict__ x,
                                                 const float* __restrict__ g,
                                                 bf16* __restrict__ out_pad, int D, int T) {
  const long row = blockIdx.x;
  const long b = row / T, t = row - b * T;
  const float* xr = x + row * (long)D;
  bf16* orow = out_pad + (b * (long)(T + 1) + t + 1) * D;
  const int tid = threadIdx.x;
  const float4 xv = *(const float4*)&xr[tid * 4];
  float ss = xv.x * xv.x + xv.y * xv.y + xv.z * xv.z + xv.w * xv.w;
  for (int off = 32; off; off >>= 1) ss += __shfl_down(ss, off);
  __shared__ float sred[4];
  if ((tid & 63) == 0) sred[tid >> 6] = ss;
  __syncthreads();
  const float tot = sred[0] + sred[1] + sred[2] + sred[3];
  const float scale = rsqrtf(tot / (float)D + 1e-6f);
  const float4 gv = *(const float4*)&g[tid * 4];
  bf16 o4[4];
  o4[0] = __float2bfloat16(xv.x * scale * gv.x);
  o4[1] = __float2bfloat16(xv.y * scale * gv.y);
  o4[2] = __float2bfloat16(xv.z * scale * gv.z);
  o4[3] = __float2bfloat16(xv.w * scale * gv.w);
  *(ushort4*)(orow + tid * 4) = *(ushort4*)o4;
}

// zero the pad row (row 0) of each batch's padded out buffer
__global__ __launch_bounds__(256) void zpad_k(bf16* __restrict__ out_pad, int D, int T) {
  bf16* r = out_pad + (long)blockIdx.x * (T + 1) * D;
  ((ushort4*)r)[threadIdx.x] = make_ushort4(0, 0, 0, 0);
}

// f32 -> bf16
__global__ __launch_bounds__(256) void f2bf_k(const float* __restrict__ s, bf16* __restrict__ d, long n) {
  const long i = ((long)blockIdx.x * 256 + threadIdx.x) * 4;
  if (i >= n) return;
  const float4 v = *(const float4*)(s + i);
  bf16 o4[4] = {__float2bfloat16(v.x), __float2bfloat16(v.y),
                __float2bfloat16(v.z), __float2bfloat16(v.w)};
  *(ushort4*)(d + i) = *(ushort4*)o4;
}

__device__ __forceinline__ float4 load_bf4(const bf16* p) {
  const ushort4 u = *(const ushort4*)p;
  float4 f;
  f.x = __bfloat162float(*(const bf16*)&u.x);
  f.y = __bfloat162float(*(const bf16*)&u.y);
  f.z = __bfloat162float(*(const bf16*)&u.z);
  f.w = __bfloat162float(*(const bf16*)&u.w);
  return f;
}
__device__ __forceinline__ void store_bf4(bf16* p, float4 f) {
  bf16 o4[4] = {__float2bfloat16(f.x), __float2bfloat16(f.y),
                __float2bfloat16(f.z), __float2bfloat16(f.w)};
  *(ushort4*)p = *(ushort4*)o4;
}

// Horner combine: S_ch = a^ch W + sum_{j<ch} a^{ch-1-j} P_j ; W_new = S_NC (f32)
__global__ __launch_bounds__(256) void comb_k(const float* __restrict__ W,
                                              const bf16* __restrict__ P,
                                              bf16* __restrict__ Sch,
                                              float* __restrict__ Wn,
                                              const float* __restrict__ dec,
                                              long DDl, int NC) {
  const long i = ((long)blockIdx.x * 256 + threadIdx.x) * 4;
  const int b = (int)(i / DDl);
  const long e = i - (long)b * DDl;
  const float lg = -log1pf(expf(-dec[0]));
  const float a = __expf(lg * (float)CH);
  float4 s = *(const float4*)(W + i);
  store_bf4(Sch + ((long)b * NC) * DDl + e, s);            // S_0 = W
  for (int ch = 0; ch < NC; ch++) {
    const float4 pp = load_bf4(P + ((long)b * NC + ch) * DDl + e);
    s.x = a * s.x + pp.x;  s.y = a * s.y + pp.y;
    s.z = a * s.z + pp.z;  s.w = a * s.w + pp.w;
    if (ch + 1 < NC) store_bf4(Sch + ((long)b * NC + ch + 1) * DDl + e, s);
  }
  *(float4*)(Wn + i) = s;                                  // W_new = S_NC
}

// transpose [T][D] -> [NC][D][CH]; WK=1: read padded src (wk shift) and fold decay weight
template<int WK>
__global__ __launch_bounds__(256) void tr_k(const bf16* __restrict__ src, bf16* __restrict__ dst,
                                            const float* __restrict__ dec, int D, int T, int NC) {
  __shared__ bf16 tl[32][33];
  const int b = blockIdx.z, d0 = blockIdx.x * 32, tg0 = blockIdx.y * 32;
  const int tx = threadIdx.x, ty = threadIdx.y;
  const float lg = -log1pf(expf(-dec[0]));
  for (int i = ty; i < 32; i += 8) {
    const int tg = tg0 + i;
    float val;
    if (WK)  // src row tg of padded buffer == out[tg-1] == wk[tg]
      val = __expf(lg * (float)(CH - 1 - (tg & (CH - 1)))) *
            __bfloat162float(src[((long)b * (T + 1) + tg) * D + d0 + tx]);
    else
      val = __bfloat162float(src[((long)b * T + tg) * D + d0 + tx]);
    tl[i][tx] = __float2bfloat16(val);
  }
  __syncthreads();
  const int ch = tg0 >> LC, tc0 = tg0 & (CH - 1);
  for (int i = ty; i < 32; i += 8)
    dst[(((long)b * NC + ch) * D + d0 + i) * CH + tc0 + tx] = tl[tx][i];
}

extern "C" void kernel_launch(void* const* d_in, const int* in_sizes, int n_in,
                              void* d_out, int out_size, void* d_ws, size_t ws_size,
                              hipStream_t stream) {
  const float* x     = (const float*)d_in[0];
  const float* W     = (const float*)d_in[1];
  const float* g     = (const float*)d_in[2];
  const float* Wpw   = (const float*)d_in[3];
  const float* Wpr   = (const float*)d_in[4];
  const float* decay = (const float*)d_in[5];

  const int D  = in_sizes[2];                 // 1024
  const int Bn = in_sizes[1] / (D * D);       // 4
  const int T  = in_sizes[0] / (Bn * D);      // 4096
  const int NC = T / CH;                      // 4 chunks
  const long TD = (long)T * D, DD = (long)D * D, PD = (long)(T + 1) * D;

  // workspace (all bf16): 196.1 MB. Aliases: v_rm=scores (pre/post), Sch=wkTw (dead after P).
  bf16* out_pad  = (bf16*)d_ws;                       // [B][T+1][D]
  bf16* vT       = out_pad + Bn * PD;                 // [B][NC][D][CH]
  bf16* wkTw     = vT + Bn * TD;                      // [B][NC][D][CH]; later Sch
  bf16* scores   = wkTw + Bn * TD;                    // [B][NC][CH][CH]; aliases v_rm
  bf16* P_bf     = scores + (long)Bn * NC * CH * CH;  // [B][NC][D][D]
  bf16* Wpw_bf   = P_bf + (long)Bn * NC * DD;         // [D][D]
  bf16* Wpr_bf   = Wpw_bf + DD;                       // [D][D]
  bf16* reads_bf = Wpr_bf + DD;                       // [B][T][D]
  bf16* v_rm     = scores;                            // row-major v (pre-scores)
  bf16* Sch      = wkTw;                              // [B][NC][D][D] (post-P)

  float* y = (float*)d_out;                           // [B][T][D]
  float* S = y + Bn * TD;                             // [B][D][D] == W_new

  // 1) rmsnorm -> out_pad (row t+1); zero pad rows; convert weights
  rmsnorm_k<<<Bn * T, D / 4, 0, stream>>>(x, g, out_pad, D, T);
  zpad_k<<<Bn, 256, 0, stream>>>(out_pad, D, T);
  f2bf_k<<<(int)(DD / 1024), 256, 0, stream>>>(Wpw, Wpw_bf, DD);
  f2bf_k<<<(int)(DD / 1024), 256, 0, stream>>>(Wpr, Wpr_bf, DD);

  // 2) v_rm = out @ Wp_w^T
  {
    MGP p{}; p.dec = decay;
    p.A = out_pad; p.lda = D; p.sAb = PD; p.aOff0 = 1;
    p.B = Wpw_bf;  p.ldb = D;
    p.Cb = v_rm; p.ldc = D; p.sCbb = TD;
    p.K = D; p.NC = 1;
    mg_k<E_BF><<<dim3(T / 128, D / 128, Bn), TPB, 0, stream>>>(p);
  }
  // 3) vT / wkTw transposes
  tr_k<0><<<dim3(D / 32, T / 32, Bn), dim3(32, 8), 0, stream>>>(v_rm, vT, decay, D, T, NC);
  tr_k<1><<<dim3(D / 32, T / 32, Bn), dim3(32, 8), 0, stream>>>(out_pad, wkTw, decay, D, T, NC);
  // 4) P_ch = vT_ch @ wkTw_ch^T
  {
    MGP p{}; p.dec = decay;
    p.A = vT;   p.lda = CH; p.sAb = TD; p.aStep = D;
    p.B = wkTw; p.ldb = CH; p.sBb = TD; p.bStep = D;
    p.Cb = P_bf; p.ldc = D; p.sCbb = (long)NC * DD; p.sCkb = DD;
    p.K = CH; p.NC = NC;
    mg_k<E_P><<<dim3(D / 128, D / 128, Bn * NC), TPB, 0, stream>>>(p);
  }
  // 5) Horner combine -> Sch (over dead wkTw) + W_new
  comb_k<<<(int)(Bn * DD / 1024), 256, 0, stream>>>(W, P_bf, Sch, S, decay, DD, NC);
  // 6) intra-chunk scores (lower-triangle blocks only; overwrites v_rm)
  {
    MGP p{}; p.dec = decay;
    p.A = out_pad; p.lda = D; p.sAb = PD; p.aOff0 = 1; p.aStep = CH;
    p.B = out_pad; p.ldb = D; p.sBb = PD; p.bOff0 = 0; p.bStep = CH;
    p.Cb = scores; p.ldc = CH; p.sCbb = (long)NC * CH * CH; p.sCkb = (long)CH * CH;
    p.K = D; p.NC = NC;
    mg_k<E_SCORES><<<dim3(CH / 128, CH / 128, Bn * NC), TPB, 0, stream>>>(p);
  }
  // 7) FUSED reads = e^{lg tc}*(out_ch @ Sch^T) + scores @ v (K truncated at diag)
  {
    MGP p{}; p.dec = decay;
    p.A2 = out_pad; p.lda2 = D; p.sA2b = PD; p.a2Off0 = 1; p.a2Step = CH;
    p.B2 = Sch;     p.ldb2 = D; p.sB2b = (long)NC * DD; p.b2Step = D;
    p.K2 = D;
    p.A = scores; p.lda = CH; p.sAb = (long)NC * CH * CH; p.aStep = CH;
    p.B = vT;     p.ldb = CH; p.sBb = TD; p.bStep = D;
    p.Cb = reads_bf; p.ldc = D; p.sCbb = TD; p.sCkb = (long)CH * D;
    p.K = CH; p.NC = NC;
    mg_k<E_RDF><<<dim3(CH / 128, D / 128, Bn * NC), TPB, 0, stream>>>(p);
  }
  // 8) y = x + out + 0.03 * reads @ Wp_r^T
  {
    MGP p{}; p.dec = decay;
    p.A = reads_bf; p.lda = D; p.sAb = TD;
    p.B = Wpr_bf;   p.ldb = D;
    p.Cf = y; p.ldc = D; p.sCfb = TD;
    p.X = x; p.O = out_pad; p.sOb = PD;
    p.K = D; p.NC = 1;
    mg_k<E_FINAL><<<dim3(T / 128, D / 128, Bn), TPB, 0, stream>>>(p);
  }
}